// Round 1
// baseline (1422.688 us; speedup 1.0000x reference)
//
#include <hip/hip_runtime.h>
#include <math.h>

#define Nn 20000
#define Ee 640000
#define ETOT 660000   // Ee + Nn self loops
#define NF 512
#define C1 256        // HEADS*NHID
#define C2 64         // NOUT
#define KC 100
#define TEMP 5.0f
#define NSLOPE 0.2f
#define NPART 256     // partial blocks for cluster_mean
#define CHN 79        // nodes per cmean block = ceil(20000/256)

__device__ __forceinline__ float wredSum(float v) {
#pragma unroll
  for (int off = 32; off > 0; off >>= 1) v += __shfl_xor(v, off, 64);
  return v;
}
__device__ __forceinline__ float wredMax(float v) {
#pragma unroll
  for (int off = 32; off > 0; off >>= 1) v = fmaxf(v, __shfl_xor(v, off, 64));
  return v;
}
__device__ __forceinline__ float bredSum(float v, volatile float* red) {
  v = wredSum(v);
  __syncthreads();
  if ((threadIdx.x & 63) == 0) red[threadIdx.x >> 6] = v;
  __syncthreads();
  return red[0] + red[1] + red[2] + red[3];
}
__device__ __forceinline__ float bredMax(float v, volatile float* red) {
  v = wredMax(v);
  __syncthreads();
  if ((threadIdx.x & 63) == 0) red[threadIdx.x >> 6] = v;
  __syncthreads();
  return fmaxf(fmaxf(red[0], red[1]), fmaxf(red[2], red[3]));
}

// ---------------- CSR build ----------------
__global__ void hist_kernel(const int* __restrict__ ei, int* __restrict__ deg) {
  int e = blockIdx.x * 256 + threadIdx.x;
  if (e >= ETOT) return;
  int dst = e < Ee ? ei[Ee + e] : e - Ee;
  atomicAdd(&deg[dst], 1);
}

__global__ __launch_bounds__(1024) void scan_kernel(const int* __restrict__ deg,
    int* __restrict__ rowp, int* __restrict__ curs) {
  __shared__ int buf[1024];
  __shared__ int carry;
  int tid = threadIdx.x;
  if (tid == 0) { carry = 0; rowp[0] = 0; }
  __syncthreads();
  for (int base = 0; base < Nn; base += 1024) {
    int i = base + tid;
    int v = (i < Nn) ? deg[i] : 0;
    int x = v;
    buf[tid] = x;
    __syncthreads();
    for (int off = 1; off < 1024; off <<= 1) {
      int t = (tid >= off) ? buf[tid - off] : 0;
      __syncthreads();
      x += t;
      buf[tid] = x;
      __syncthreads();
    }
    int inc = x + carry;
    if (i < Nn) { rowp[i + 1] = inc; curs[i] = inc - v; }
    __syncthreads();
    if (tid == 1023) carry = inc;
    __syncthreads();
  }
}

__global__ void scatter_kernel(const int* __restrict__ ei, int* __restrict__ curs,
                               int* __restrict__ esort) {
  int e = blockIdx.x * 256 + threadIdx.x;
  if (e >= ETOT) return;
  int dst = e < Ee ? ei[Ee + e] : e - Ee;
  int pos = atomicAdd(&curs[dst], 1);
  esort[pos] = e;
}

// ---------------- f32 GEMM: C[M,N] = A[M,K] @ B[N,K]^T ----------------
__global__ __launch_bounds__(256) void gemm_nt(const float* __restrict__ A,
    const float* __restrict__ B, float* __restrict__ C, int M, int N, int K) {
  __shared__ __align__(16) float As[16][68];
  __shared__ __align__(16) float Bs[16][68];
  int tid = threadIdx.x;
  int bm = blockIdx.x << 6, bn = blockIdx.y << 6;
  int lr = tid >> 2;
  int lc = (tid & 3) << 2;
  int tx = tid & 15, ty = tid >> 4;
  float acc[4][4] = {};
  for (int k0 = 0; k0 < K; k0 += 16) {
    int am = bm + lr;
    float4 av = make_float4(0.f, 0.f, 0.f, 0.f);
    if (am < M) av = *(const float4*)(A + (size_t)am * K + k0 + lc);
    float4 bv = *(const float4*)(B + (size_t)(bn + lr) * K + k0 + lc);
    __syncthreads();
    As[lc + 0][lr] = av.x; As[lc + 1][lr] = av.y; As[lc + 2][lr] = av.z; As[lc + 3][lr] = av.w;
    Bs[lc + 0][lr] = bv.x; Bs[lc + 1][lr] = bv.y; Bs[lc + 2][lr] = bv.z; Bs[lc + 3][lr] = bv.w;
    __syncthreads();
#pragma unroll
    for (int k = 0; k < 16; k++) {
      float4 a = *(const float4*)&As[k][ty << 2];
      float4 b = *(const float4*)&Bs[k][tx << 2];
      float aa[4] = {a.x, a.y, a.z, a.w};
      float bb[4] = {b.x, b.y, b.z, b.w};
#pragma unroll
      for (int i = 0; i < 4; i++)
#pragma unroll
        for (int j = 0; j < 4; j++) acc[i][j] += aa[i] * bb[j];
    }
  }
#pragma unroll
  for (int i = 0; i < 4; i++) {
    int row = bm + (ty << 2) + i;
    if (row < M) {
#pragma unroll
      for (int j = 0; j < 4; j++)
        C[(size_t)row * N + bn + (tx << 2) + j] = acc[i][j];
    }
  }
}

// ---------------- per-node attention scalars ----------------
__global__ __launch_bounds__(256) void alpha1_kernel(const float* __restrict__ h,
    const float* __restrict__ a_src, const float* __restrict__ a_dst,
    float* __restrict__ asn, float* __restrict__ adn) {
  int l = threadIdx.x & 63;
  int n = (blockIdx.x << 2) + (threadIdx.x >> 6);
  if (n >= Nn) return;
  const float* hr = h + (size_t)n * C1;
  float h0 = hr[l], h1v = hr[64 + l], h2v = hr[128 + l], h3v = hr[192 + l];
  float ps0 = h0 * a_src[l] + h1v * a_src[64 + l];
  float pd0 = h0 * a_dst[l] + h1v * a_dst[64 + l];
  float ps1 = h2v * a_src[128 + l] + h3v * a_src[192 + l];
  float pd1 = h2v * a_dst[128 + l] + h3v * a_dst[192 + l];
  ps0 = wredSum(ps0); pd0 = wredSum(pd0); ps1 = wredSum(ps1); pd1 = wredSum(pd1);
  if (l == 0) {
    asn[2 * n] = ps0; asn[2 * n + 1] = ps1;
    adn[2 * n] = pd0; adn[2 * n + 1] = pd1;
  }
}

__global__ __launch_bounds__(256) void alpha2_kernel(const float* __restrict__ h,
    const float* __restrict__ a_src, const float* __restrict__ a_dst,
    float* __restrict__ asn, float* __restrict__ adn) {
  int l = threadIdx.x & 63;
  int n = (blockIdx.x << 2) + (threadIdx.x >> 6);
  if (n >= Nn) return;
  float v = h[(size_t)n * C2 + l];
  float ps = wredSum(v * a_src[l]);
  float pd = wredSum(v * a_dst[l]);
  if (l == 0) { asn[n] = ps; adn[n] = pd; }
}

// ---------------- layer 1 segment softmax + aggregate + bias + ELU ----------------
__global__ __launch_bounds__(256) void agg1_kernel(const float* __restrict__ h,
    const float* __restrict__ asn, const float* __restrict__ adn,
    const float* __restrict__ b1, const int* __restrict__ ei,
    const int* __restrict__ rowp, const int* __restrict__ esort,
    float* __restrict__ ho) {
  __shared__ float red[4];
  __shared__ float w0[64], w1[64];
  __shared__ int ss[64];
  int n = blockIdx.x, tid = threadIdx.x;
  int lo = rowp[n], hi = rowp[n + 1];
  float ad0 = adn[2 * n], ad1 = adn[2 * n + 1];
  float m0 = -1e30f, m1 = -1e30f;
  for (int i = lo + tid; i < hi; i += 256) {
    int eid = esort[i];
    int s = eid < Ee ? ei[eid] : eid - Ee;
    float e0 = asn[2 * s] + ad0;     e0 = e0 > 0.f ? e0 : NSLOPE * e0;
    float e1 = asn[2 * s + 1] + ad1; e1 = e1 > 0.f ? e1 : NSLOPE * e1;
    m0 = fmaxf(m0, e0); m1 = fmaxf(m1, e1);
  }
  m0 = bredMax(m0, red);
  m1 = bredMax(m1, red);
  float s0 = 0.f, s1 = 0.f;
  for (int i = lo + tid; i < hi; i += 256) {
    int eid = esort[i];
    int s = eid < Ee ? ei[eid] : eid - Ee;
    float e0 = asn[2 * s] + ad0;     e0 = e0 > 0.f ? e0 : NSLOPE * e0;
    float e1 = asn[2 * s + 1] + ad1; e1 = e1 > 0.f ? e1 : NSLOPE * e1;
    s0 += expf(e0 - m0); s1 += expf(e1 - m1);
  }
  s0 = bredSum(s0, red) + 1e-16f;
  s1 = bredSum(s1, red) + 1e-16f;
  float r0 = 1.0f / s0, r1 = 1.0f / s1;
  float acc = 0.f;
  int c = tid;
  const bool hi_head = (tid & 128) != 0;
  for (int base = lo; base < hi; base += 64) {
    int cnt = min(64, hi - base);
    __syncthreads();
    if (tid < cnt) {
      int eid = esort[base + tid];
      int s = eid < Ee ? ei[eid] : eid - Ee;
      float e0 = asn[2 * s] + ad0;     e0 = e0 > 0.f ? e0 : NSLOPE * e0;
      float e1 = asn[2 * s + 1] + ad1; e1 = e1 > 0.f ? e1 : NSLOPE * e1;
      w0[tid] = expf(e0 - m0) * r0;
      w1[tid] = expf(e1 - m1) * r1;
      ss[tid] = s;
    }
    __syncthreads();
    const float* hw = hi_head ? w1 : w0;
    for (int j = 0; j < cnt; j++)
      acc += h[(size_t)ss[j] * C1 + c] * hw[j];
  }
  float v = acc + b1[c];
  ho[(size_t)n * C1 + c] = v > 0.f ? v : expf(v) - 1.0f;   // ELU
}

// ---------------- layer 2 segment softmax + aggregate + bias + eps + normalize ----------------
__global__ __launch_bounds__(64) void agg2_kernel(const float* __restrict__ h,
    const float* __restrict__ asn, const float* __restrict__ adn,
    const float* __restrict__ b2, const int* __restrict__ ei,
    const int* __restrict__ rowp, const int* __restrict__ esort,
    float* __restrict__ emb, float* __restrict__ dnrm) {
  __shared__ float wv[64];
  __shared__ int ss[64];
  int n = blockIdx.x, l = threadIdx.x;
  int lo = rowp[n], hi = rowp[n + 1];
  float ad = adn[n];
  float m = -1e30f;
  for (int i = lo + l; i < hi; i += 64) {
    int eid = esort[i];
    int s = eid < Ee ? ei[eid] : eid - Ee;
    float e = asn[s] + ad; e = e > 0.f ? e : NSLOPE * e;
    m = fmaxf(m, e);
  }
  m = wredMax(m);
  float sum = 0.f;
  for (int i = lo + l; i < hi; i += 64) {
    int eid = esort[i];
    int s = eid < Ee ? ei[eid] : eid - Ee;
    float e = asn[s] + ad; e = e > 0.f ? e : NSLOPE * e;
    sum += expf(e - m);
  }
  sum = wredSum(sum) + 1e-16f;
  float rs = 1.0f / sum;
  float acc = 0.f;
  for (int base = lo; base < hi; base += 64) {
    int cnt = min(64, hi - base);
    __syncthreads();
    if (l < cnt) {
      int eid = esort[base + l];
      int s = eid < Ee ? ei[eid] : eid - Ee;
      float e = asn[s] + ad; e = e > 0.f ? e : NSLOPE * e;
      wv[l] = expf(e - m) * rs;
      ss[l] = s;
    }
    __syncthreads();
    for (int j = 0; j < cnt; j++)
      acc += h[(size_t)ss[j] * C2 + l] * wv[j];
  }
  float e = acc + b2[l] + 1e-6f;
  float nrm = sqrtf(wredSum(e * e));
  emb[(size_t)n * C2 + l] = e;
  dnrm[(size_t)n * C2 + l] = e / nrm;
}

// ---------------- clustering ----------------
// r = softmax(TEMP * data_n @ mu^T) per row; optionally write dist (FINAL)
template <bool FINAL>
__global__ __launch_bounds__(256) void assign_kernel(
    const float* __restrict__ dnp, const float* __restrict__ mu,
    float* __restrict__ rout, float* __restrict__ distout,
    int it, const int* __restrict__ niter) {
  if (!FINAL) { if (it > niter[0]) return; }
  __shared__ float mu_s[KC * 65];
  __shared__ float dn_s[4][4][64];
  int tid = threadIdx.x;
  for (int idx = tid; idx < KC * 64; idx += 256)
    mu_s[(idx >> 6) * 65 + (idx & 63)] = mu[idx];
  __syncthreads();
  int wave = tid >> 6, l = tid & 63;
  const bool has2 = l < (KC - 64);
  int l2 = has2 ? 64 + l : l;
  for (int i = 0; i < 5; i++) {
    size_t nb0 = (size_t)blockIdx.x * 80 + wave * 20 + i * 4;
#pragma unroll
    for (int nb = 0; nb < 4; nb++)
      dn_s[wave][nb][l] = dnp[(nb0 + nb) * C2 + l];
    __syncthreads();
    float z1[4] = {0.f, 0.f, 0.f, 0.f}, z2[4] = {0.f, 0.f, 0.f, 0.f};
#pragma unroll 8
    for (int d = 0; d < 64; d++) {
      float m1v = mu_s[l * 65 + d];
      float m2v = mu_s[l2 * 65 + d];
#pragma unroll
      for (int nb = 0; nb < 4; nb++) {
        float dv = dn_s[wave][nb][d];
        z1[nb] += m1v * dv;
        z2[nb] += m2v * dv;
      }
    }
#pragma unroll
    for (int nb = 0; nb < 4; nb++) {
      float g1 = TEMP * z1[nb];
      float g2 = has2 ? TEMP * z2[nb] : -1e30f;
      float m = wredMax(fmaxf(g1, g2));
      float e1 = expf(g1 - m);
      float e2 = has2 ? expf(g2 - m) : 0.f;
      float s = wredSum(e1 + e2);
      float inv = 1.0f / s;
      size_t n = nb0 + nb;
      rout[n * KC + l] = e1 * inv;
      if (has2) rout[n * KC + 64 + l] = e2 * inv;
      if (FINAL) {
        distout[n * KC + l] = z1[nb];
        if (has2) distout[n * KC + 64 + l] = z2[nb];
      }
    }
    __syncthreads();
  }
}

// partial cluster_mean[k][d] and cluster_r[k] per block over its node chunk
__global__ __launch_bounds__(256) void cmean_kernel(const float* __restrict__ rb,
    const float* __restrict__ dnp, float* __restrict__ pcm, float* __restrict__ pcr,
    int it, const int* __restrict__ niter) {
  if (it > niter[0]) return;
  __shared__ float r_s[32 * 100];
  __shared__ __align__(16) float d_s[32 * 68];
  int tid = threadIdx.x, b = blockIdx.x;
  int tx = tid & 15, ky = tid >> 4;
  float acc[7][4] = {};
  float accr[7] = {};
  int node0 = b * CHN;
  for (int sc = 0; sc < 3; sc++) {
    int base = node0 + sc * 32;
    int nv = CHN - sc * 32; if (nv > 32) nv = 32;
    int nv2 = Nn - base;    if (nv2 < nv) nv = nv2;
    if (nv < 0) nv = 0;
    __syncthreads();
    for (int idx = tid; idx < 3200; idx += 256)
      r_s[idx] = (idx < nv * 100) ? rb[(size_t)base * 100 + idx] : 0.f;
    for (int idx = tid; idx < 2048; idx += 256) {
      int row = idx >> 6, col = idx & 63;
      d_s[row * 68 + col] = (idx < nv * 64) ? dnp[(size_t)base * 64 + idx] : 0.f;
    }
    __syncthreads();
    for (int j = 0; j < 32; j++) {
      float4 dv = *(const float4*)&d_s[j * 68 + (tx << 2)];
#pragma unroll
      for (int jj = 0; jj < 7; jj++) {
        int kk = ky + (jj << 4);
        if (kk < KC) {
          float rv = r_s[j * 100 + kk];
          acc[jj][0] += rv * dv.x; acc[jj][1] += rv * dv.y;
          acc[jj][2] += rv * dv.z; acc[jj][3] += rv * dv.w;
          if (tx == 0) accr[jj] += rv;
        }
      }
    }
  }
#pragma unroll
  for (int jj = 0; jj < 7; jj++) {
    int kk = ky + (jj << 4);
    if (kk < KC) {
      float* p = pcm + (size_t)b * 6400 + kk * 64 + (tx << 2);
      p[0] = acc[jj][0]; p[1] = acc[jj][1]; p[2] = acc[jj][2]; p[3] = acc[jj][3];
      if (tx == 0) pcr[b * 100 + kk] = accr[jj];
    }
  }
}

// mu[k][d] = sum_b pcm[b][k*64+d] / sum_b pcr[b][k]
__global__ __launch_bounds__(256) void muupd_kernel(const float* __restrict__ pcm,
    const float* __restrict__ pcr, float* __restrict__ mu,
    int it, const int* __restrict__ niter) {
  if (it > niter[0]) return;
  __shared__ float part[4][64];
  __shared__ float red[4];
  int k = blockIdx.x, tid = threadIdx.x;
  int d = tid & 63, bg = tid >> 6;
  float s = 0.f;
  for (int b = bg; b < NPART; b += 4)
    s += pcm[(size_t)b * 6400 + k * 64 + d];
  part[bg][d] = s;
  float c = pcr[tid * 100 + k];
  c = wredSum(c);
  if ((tid & 63) == 0) red[tid >> 6] = c;
  __syncthreads();
  if (tid < 64) {
    float cr = red[0] + red[1] + red[2] + red[3];
    mu[k * 64 + tid] = (part[0][tid] + part[1][tid] + part[2][tid] + part[3][tid]) / cr;
  }
}

__global__ void copy_f(const float* __restrict__ a, float* __restrict__ b, int n) {
  int i = blockIdx.x * 256 + threadIdx.x;
  if (i < n) b[i] = a[i];
}

extern "C" void kernel_launch(void* const* d_in, const int* in_sizes, int n_in,
                              void* d_out, int out_size, void* d_ws, size_t ws_size,
                              hipStream_t stream) {
  const float* x    = (const float*)d_in[0];
  const float* W1   = (const float*)d_in[1];
  const float* asr1 = (const float*)d_in[2];
  const float* ads1 = (const float*)d_in[3];
  const float* b1   = (const float*)d_in[4];
  const float* W2   = (const float*)d_in[5];
  const float* asr2 = (const float*)d_in[6];
  const float* ads2 = (const float*)d_in[7];
  const float* b2   = (const float*)d_in[8];
  const float* mu0  = (const float*)d_in[9];
  const int*   ei   = (const int*)d_in[10];
  const int*   nit  = (const int*)d_in[11];

  float* f = (float*)d_ws;
  float* h1   = f;  f += (size_t)Nn * C1;
  float* h1o  = f;  f += (size_t)Nn * C1;
  float* as1  = f;  f += Nn * 2;
  float* ad1  = f;  f += Nn * 2;
  float* h2   = f;  f += (size_t)Nn * C2;
  float* as2  = f;  f += Nn;
  float* ad2  = f;  f += Nn;
  float* dn   = f;  f += (size_t)Nn * C2;
  float* rbuf = f;  f += (size_t)Nn * KC;
  float* pcm  = f;  f += (size_t)NPART * 6400;
  float* pcr  = f;  f += NPART * 100;
  float* mu   = f;  f += KC * C2;
  int* ip = (int*)f;
  int* deg   = ip;  ip += Nn;
  int* rowp  = ip;  ip += Nn + 1;
  int* curs  = ip;  ip += Nn;
  int* esort = ip;  ip += ETOT;

  float* out_mu = (float*)d_out;
  float* out_r  = out_mu + KC * C2;
  float* out_e  = out_r + (size_t)Nn * KC;
  float* out_d  = out_e + (size_t)Nn * C2;

  hipMemsetAsync(deg, 0, Nn * sizeof(int), stream);
  hist_kernel<<<(ETOT + 255) / 256, 256, 0, stream>>>(ei, deg);
  scan_kernel<<<1, 1024, 0, stream>>>(deg, rowp, curs);
  scatter_kernel<<<(ETOT + 255) / 256, 256, 0, stream>>>(ei, curs, esort);

  gemm_nt<<<dim3(313, 4), 256, 0, stream>>>(x, W1, h1, Nn, C1, NF);
  alpha1_kernel<<<5000, 256, 0, stream>>>(h1, asr1, ads1, as1, ad1);
  agg1_kernel<<<Nn, 256, 0, stream>>>(h1, as1, ad1, b1, ei, rowp, esort, h1o);

  gemm_nt<<<dim3(313, 1), 256, 0, stream>>>(h1o, W2, h2, Nn, C2, C1);
  alpha2_kernel<<<5000, 256, 0, stream>>>(h2, asr2, ads2, as2, ad2);
  agg2_kernel<<<Nn, 64, 0, stream>>>(h2, as2, ad2, b2, ei, rowp, esort, out_e, dn);

  copy_f<<<25, 256, 0, stream>>>(mu0, mu, KC * C2);
  for (int it = 0; it < 12; it++) {   // guarded on device by num_iter (runs niter+1 = 11)
    assign_kernel<false><<<250, 256, 0, stream>>>(dn, mu, rbuf, nullptr, it, nit);
    cmean_kernel<<<NPART, 256, 0, stream>>>(rbuf, dn, pcm, pcr, it, nit);
    muupd_kernel<<<KC, 256, 0, stream>>>(pcm, pcr, mu, it, nit);
  }
  assign_kernel<true><<<250, 256, 0, stream>>>(dn, mu, out_r, out_d, 0, nit);
  copy_f<<<25, 256, 0, stream>>>(mu, out_mu, KC * C2);
}

// Round 2
// 1173.434 us; speedup vs baseline: 1.2124x; 1.2124x over previous
//
#include <hip/hip_runtime.h>
#include <math.h>

#define Nn 20000
#define Ee 640000
#define ETOT 660000   // Ee + Nn self loops
#define NF 512
#define C1 256        // HEADS*NHID
#define C2 64         // NOUT
#define KC 100
#define TEMP 5.0f
#define NSLOPE 0.2f
#define NPART 250     // blocks for fused assign+cmean (250*80 = 20000 exactly)
#define CHB 80        // nodes per fused block

__device__ __forceinline__ float wredSum(float v) {
#pragma unroll
  for (int off = 32; off > 0; off >>= 1) v += __shfl_xor(v, off, 64);
  return v;
}
__device__ __forceinline__ float wredMax(float v) {
#pragma unroll
  for (int off = 32; off > 0; off >>= 1) v = fmaxf(v, __shfl_xor(v, off, 64));
  return v;
}
__device__ __forceinline__ float bredSum(float v, volatile float* red) {
  v = wredSum(v);
  __syncthreads();
  if ((threadIdx.x & 63) == 0) red[threadIdx.x >> 6] = v;
  __syncthreads();
  return red[0] + red[1] + red[2] + red[3];
}
__device__ __forceinline__ float bredMax(float v, volatile float* red) {
  v = wredMax(v);
  __syncthreads();
  if ((threadIdx.x & 63) == 0) red[threadIdx.x >> 6] = v;
  __syncthreads();
  return fmaxf(fmaxf(red[0], red[1]), fmaxf(red[2], red[3]));
}

// ---------------- CSR build ----------------
__global__ void hist_kernel(const int* __restrict__ ei, int* __restrict__ deg) {
  int e = blockIdx.x * 256 + threadIdx.x;
  if (e >= ETOT) return;
  int dst = e < Ee ? ei[Ee + e] : e - Ee;
  atomicAdd(&deg[dst], 1);
}

// single block, 1024 threads; thread t owns 20 elements. 2 barriers total.
__global__ __launch_bounds__(1024) void scan2_kernel(const int* __restrict__ deg,
    int* __restrict__ rowp, int* __restrict__ curs) {
  __shared__ int wsum[16];
  __shared__ int wpre[16];
  int t = threadIdx.x;
  int lane = t & 63, w = t >> 6;
  int loc[20];
  int tot = 0;
  int base = t * 20;
  if (t < 1000) {
#pragma unroll
    for (int i = 0; i < 20; i++) { tot += deg[base + i]; loc[i] = tot; }
  }
  int s = tot;
#pragma unroll
  for (int off = 1; off < 64; off <<= 1) {
    int u = __shfl_up(s, off, 64);
    if (lane >= off) s += u;
  }
  if (lane == 63) wsum[w] = s;
  __syncthreads();
  if (t == 0) {
    int c = 0;
#pragma unroll
    for (int i = 0; i < 16; i++) { c += wsum[i]; wpre[i] = c; }
    rowp[0] = 0;
  }
  __syncthreads();
  int p = (w > 0 ? wpre[w - 1] : 0) + s - tot;   // exclusive prefix for this thread
  if (t < 1000) {
    int prev = 0;
#pragma unroll
    for (int i = 0; i < 20; i++) {
      rowp[base + i + 1] = p + loc[i];
      curs[base + i] = p + prev;
      prev = loc[i];
    }
  }
}

__global__ void scatter_kernel(const int* __restrict__ ei, int* __restrict__ curs,
                               int* __restrict__ esort) {
  int e = blockIdx.x * 256 + threadIdx.x;
  if (e >= ETOT) return;
  int dst = e < Ee ? ei[Ee + e] : e - Ee;
  int pos = atomicAdd(&curs[dst], 1);
  esort[pos] = e;
}

// ---------------- f32 GEMM 128x128: C[M,N] = A[M,K] @ B[N,K]^T ----------------
__global__ __launch_bounds__(256) void gemm128(const float* __restrict__ A,
    const float* __restrict__ B, float* __restrict__ C, int M, int N, int K) {
  __shared__ __align__(16) float As[16][132];
  __shared__ __align__(16) float Bs[16][132];
  int tid = threadIdx.x;
  int bm = blockIdx.x << 7, bn = blockIdx.y << 7;
  int tx = tid & 15, ty = tid >> 4;
  int r0 = tid >> 2;            // 0..63
  int c0 = (tid & 3) << 2;      // 0,4,8,12
  float acc[2][2][4][4] = {};
  for (int k0 = 0; k0 < K; k0 += 16) {
    float4 a0 = make_float4(0.f, 0.f, 0.f, 0.f), a1 = a0;
    int am0 = bm + r0, am1 = bm + 64 + r0;
    if (am0 < M) a0 = *(const float4*)(A + (size_t)am0 * K + k0 + c0);
    if (am1 < M) a1 = *(const float4*)(A + (size_t)am1 * K + k0 + c0);
    float4 b0 = *(const float4*)(B + (size_t)(bn + r0) * K + k0 + c0);
    float4 b1 = *(const float4*)(B + (size_t)(bn + 64 + r0) * K + k0 + c0);
    __syncthreads();
    As[c0 + 0][r0] = a0.x; As[c0 + 1][r0] = a0.y; As[c0 + 2][r0] = a0.z; As[c0 + 3][r0] = a0.w;
    As[c0 + 0][64 + r0] = a1.x; As[c0 + 1][64 + r0] = a1.y; As[c0 + 2][64 + r0] = a1.z; As[c0 + 3][64 + r0] = a1.w;
    Bs[c0 + 0][r0] = b0.x; Bs[c0 + 1][r0] = b0.y; Bs[c0 + 2][r0] = b0.z; Bs[c0 + 3][r0] = b0.w;
    Bs[c0 + 0][64 + r0] = b1.x; Bs[c0 + 1][64 + r0] = b1.y; Bs[c0 + 2][64 + r0] = b1.z; Bs[c0 + 3][64 + r0] = b1.w;
    __syncthreads();
#pragma unroll
    for (int k = 0; k < 16; k++) {
      float4 av0 = *(const float4*)&As[k][ty << 2];
      float4 av1 = *(const float4*)&As[k][64 + (ty << 2)];
      float4 bv0 = *(const float4*)&Bs[k][tx << 2];
      float4 bv1 = *(const float4*)&Bs[k][64 + (tx << 2)];
      float aa[2][4] = {{av0.x, av0.y, av0.z, av0.w}, {av1.x, av1.y, av1.z, av1.w}};
      float bb[2][4] = {{bv0.x, bv0.y, bv0.z, bv0.w}, {bv1.x, bv1.y, bv1.z, bv1.w}};
#pragma unroll
      for (int im = 0; im < 2; im++)
#pragma unroll
        for (int i = 0; i < 4; i++)
#pragma unroll
          for (int jn = 0; jn < 2; jn++)
#pragma unroll
            for (int j = 0; j < 4; j++)
              acc[im][jn][i][j] += aa[im][i] * bb[jn][j];
    }
  }
#pragma unroll
  for (int im = 0; im < 2; im++)
#pragma unroll
    for (int i = 0; i < 4; i++) {
      int row = bm + (im << 6) + (ty << 2) + i;
      if (row < M) {
#pragma unroll
        for (int jn = 0; jn < 2; jn++) {
          float4 v = make_float4(acc[im][jn][i][0], acc[im][jn][i][1],
                                 acc[im][jn][i][2], acc[im][jn][i][3]);
          *(float4*)(C + (size_t)row * N + bn + (jn << 6) + (tx << 2)) = v;
        }
      }
    }
}

// ---------------- f32 GEMM 64x64 (for small N) ----------------
__global__ __launch_bounds__(256) void gemm_nt(const float* __restrict__ A,
    const float* __restrict__ B, float* __restrict__ C, int M, int N, int K) {
  __shared__ __align__(16) float As[16][68];
  __shared__ __align__(16) float Bs[16][68];
  int tid = threadIdx.x;
  int bm = blockIdx.x << 6, bn = blockIdx.y << 6;
  int lr = tid >> 2;
  int lc = (tid & 3) << 2;
  int tx = tid & 15, ty = tid >> 4;
  float acc[4][4] = {};
  for (int k0 = 0; k0 < K; k0 += 16) {
    int am = bm + lr;
    float4 av = make_float4(0.f, 0.f, 0.f, 0.f);
    if (am < M) av = *(const float4*)(A + (size_t)am * K + k0 + lc);
    float4 bv = *(const float4*)(B + (size_t)(bn + lr) * K + k0 + lc);
    __syncthreads();
    As[lc + 0][lr] = av.x; As[lc + 1][lr] = av.y; As[lc + 2][lr] = av.z; As[lc + 3][lr] = av.w;
    Bs[lc + 0][lr] = bv.x; Bs[lc + 1][lr] = bv.y; Bs[lc + 2][lr] = bv.z; Bs[lc + 3][lr] = bv.w;
    __syncthreads();
#pragma unroll
    for (int k = 0; k < 16; k++) {
      float4 a = *(const float4*)&As[k][ty << 2];
      float4 b = *(const float4*)&Bs[k][tx << 2];
      float aa[4] = {a.x, a.y, a.z, a.w};
      float bb[4] = {b.x, b.y, b.z, b.w};
#pragma unroll
      for (int i = 0; i < 4; i++)
#pragma unroll
        for (int j = 0; j < 4; j++) acc[i][j] += aa[i] * bb[j];
    }
  }
#pragma unroll
  for (int i = 0; i < 4; i++) {
    int row = bm + (ty << 2) + i;
    if (row < M) {
#pragma unroll
      for (int j = 0; j < 4; j++)
        C[(size_t)row * N + bn + (tx << 2) + j] = acc[i][j];
    }
  }
}

// ---------------- per-node attention scalars ----------------
__global__ __launch_bounds__(256) void alpha1_kernel(const float* __restrict__ h,
    const float* __restrict__ a_src, const float* __restrict__ a_dst,
    float* __restrict__ asn, float* __restrict__ adn) {
  int l = threadIdx.x & 63;
  int n = (blockIdx.x << 2) + (threadIdx.x >> 6);
  if (n >= Nn) return;
  const float* hr = h + (size_t)n * C1;
  float h0 = hr[l], h1v = hr[64 + l], h2v = hr[128 + l], h3v = hr[192 + l];
  float ps0 = h0 * a_src[l] + h1v * a_src[64 + l];
  float pd0 = h0 * a_dst[l] + h1v * a_dst[64 + l];
  float ps1 = h2v * a_src[128 + l] + h3v * a_src[192 + l];
  float pd1 = h2v * a_dst[128 + l] + h3v * a_dst[192 + l];
  ps0 = wredSum(ps0); pd0 = wredSum(pd0); ps1 = wredSum(ps1); pd1 = wredSum(pd1);
  if (l == 0) {
    asn[2 * n] = ps0; asn[2 * n + 1] = ps1;
    adn[2 * n] = pd0; adn[2 * n + 1] = pd1;
  }
}

__global__ __launch_bounds__(256) void alpha2_kernel(const float* __restrict__ h,
    const float* __restrict__ a_src, const float* __restrict__ a_dst,
    float* __restrict__ asn, float* __restrict__ adn) {
  int l = threadIdx.x & 63;
  int n = (blockIdx.x << 2) + (threadIdx.x >> 6);
  if (n >= Nn) return;
  float v = h[(size_t)n * C2 + l];
  float ps = wredSum(v * a_src[l]);
  float pd = wredSum(v * a_dst[l]);
  if (l == 0) { asn[n] = ps; adn[n] = pd; }
}

// ---------------- layer 1 segment softmax + aggregate + bias + ELU ----------------
__global__ __launch_bounds__(256) void agg1_kernel(const float* __restrict__ h,
    const float* __restrict__ asn, const float* __restrict__ adn,
    const float* __restrict__ b1, const int* __restrict__ ei,
    const int* __restrict__ rowp, const int* __restrict__ esort,
    float* __restrict__ ho) {
  __shared__ float red[4];
  __shared__ float w0[64], w1[64];
  __shared__ int ss[64];
  int n = blockIdx.x, tid = threadIdx.x;
  int lo = rowp[n], hi = rowp[n + 1];
  float ad0 = adn[2 * n], ad1 = adn[2 * n + 1];
  float m0 = -1e30f, m1 = -1e30f;
  for (int i = lo + tid; i < hi; i += 256) {
    int eid = esort[i];
    int s = eid < Ee ? ei[eid] : eid - Ee;
    float e0 = asn[2 * s] + ad0;     e0 = e0 > 0.f ? e0 : NSLOPE * e0;
    float e1 = asn[2 * s + 1] + ad1; e1 = e1 > 0.f ? e1 : NSLOPE * e1;
    m0 = fmaxf(m0, e0); m1 = fmaxf(m1, e1);
  }
  m0 = bredMax(m0, red);
  m1 = bredMax(m1, red);
  float s0 = 0.f, s1 = 0.f;
  for (int i = lo + tid; i < hi; i += 256) {
    int eid = esort[i];
    int s = eid < Ee ? ei[eid] : eid - Ee;
    float e0 = asn[2 * s] + ad0;     e0 = e0 > 0.f ? e0 : NSLOPE * e0;
    float e1 = asn[2 * s + 1] + ad1; e1 = e1 > 0.f ? e1 : NSLOPE * e1;
    s0 += expf(e0 - m0); s1 += expf(e1 - m1);
  }
  s0 = bredSum(s0, red) + 1e-16f;
  s1 = bredSum(s1, red) + 1e-16f;
  float r0 = 1.0f / s0, r1 = 1.0f / s1;
  float acc = 0.f;
  int c = tid;
  const bool hi_head = (tid & 128) != 0;
  for (int base = lo; base < hi; base += 64) {
    int cnt = min(64, hi - base);
    __syncthreads();
    if (tid < cnt) {
      int eid = esort[base + tid];
      int s = eid < Ee ? ei[eid] : eid - Ee;
      float e0 = asn[2 * s] + ad0;     e0 = e0 > 0.f ? e0 : NSLOPE * e0;
      float e1 = asn[2 * s + 1] + ad1; e1 = e1 > 0.f ? e1 : NSLOPE * e1;
      w0[tid] = expf(e0 - m0) * r0;
      w1[tid] = expf(e1 - m1) * r1;
      ss[tid] = s;
    }
    __syncthreads();
    const float* hw = hi_head ? w1 : w0;
    for (int j = 0; j < cnt; j++)
      acc += h[(size_t)ss[j] * C1 + c] * hw[j];
  }
  float v = acc + b1[c];
  ho[(size_t)n * C1 + c] = v > 0.f ? v : expf(v) - 1.0f;   // ELU
}

// ---------------- layer 2 segment softmax + aggregate + bias + eps + normalize ----------------
__global__ __launch_bounds__(64) void agg2_kernel(const float* __restrict__ h,
    const float* __restrict__ asn, const float* __restrict__ adn,
    const float* __restrict__ b2, const int* __restrict__ ei,
    const int* __restrict__ rowp, const int* __restrict__ esort,
    float* __restrict__ emb, float* __restrict__ dnrm) {
  __shared__ float wv[64];
  __shared__ int ss[64];
  int n = blockIdx.x, l = threadIdx.x;
  int lo = rowp[n], hi = rowp[n + 1];
  float ad = adn[n];
  float m = -1e30f;
  for (int i = lo + l; i < hi; i += 64) {
    int eid = esort[i];
    int s = eid < Ee ? ei[eid] : eid - Ee;
    float e = asn[s] + ad; e = e > 0.f ? e : NSLOPE * e;
    m = fmaxf(m, e);
  }
  m = wredMax(m);
  float sum = 0.f;
  for (int i = lo + l; i < hi; i += 64) {
    int eid = esort[i];
    int s = eid < Ee ? ei[eid] : eid - Ee;
    float e = asn[s] + ad; e = e > 0.f ? e : NSLOPE * e;
    sum += expf(e - m);
  }
  sum = wredSum(sum) + 1e-16f;
  float rs = 1.0f / sum;
  float acc = 0.f;
  for (int base = lo; base < hi; base += 64) {
    int cnt = min(64, hi - base);
    __syncthreads();
    if (l < cnt) {
      int eid = esort[base + l];
      int s = eid < Ee ? ei[eid] : eid - Ee;
      float e = asn[s] + ad; e = e > 0.f ? e : NSLOPE * e;
      wv[l] = expf(e - m) * rs;
      ss[l] = s;
    }
    __syncthreads();
    for (int j = 0; j < cnt; j++)
      acc += h[(size_t)ss[j] * C2 + l] * wv[j];
  }
  float e = acc + b2[l] + 1e-6f;
  float nrm = sqrtf(wredSum(e * e));
  emb[(size_t)n * C2 + l] = e;
  dnrm[(size_t)n * C2 + l] = e / nrm;
}

// ---------------- clustering: fused assign (+partial cluster-mean) ----------------
// MODE 0: iteration — r to LDS, partial cmean to pcm/pcr (guarded by niter)
// MODE 1: final — r and dist to global, no cmean
template <int MODE>
__global__ __launch_bounds__(256) void fused_ac(
    const float* __restrict__ dnp, const float* __restrict__ mu_init,
    const float* __restrict__ mu, float* __restrict__ pcm, float* __restrict__ pcr,
    float* __restrict__ rout, float* __restrict__ distout,
    int it, const int* __restrict__ niter) {
  if (MODE == 0) { if (it > niter[0]) return; }
  __shared__ float mu_s[KC * 65];
  __shared__ __align__(16) float d_s[CHB * 68];
  __shared__ float r_s[CHB * KC];
  int tid = threadIdx.x, blk = blockIdx.x;
  const float* msrc = (MODE == 0 && false) ? mu_init : ((MODE == 0 && it == 0) ? mu_init : mu);
  for (int idx = tid; idx < KC * 64; idx += 256)
    mu_s[(idx >> 6) * 65 + (idx & 63)] = msrc[idx];
  for (int idx = tid; idx < CHB * 64; idx += 256) {
    int row = idx >> 6, col = idx & 63;
    d_s[row * 68 + col] = dnp[(size_t)blk * (CHB * 64) + idx];
  }
  __syncthreads();
  int w = tid >> 6, l = tid & 63;
  const bool has2 = l < (KC - 64);
  int l2 = has2 ? 64 + l : l;
  for (int g = 0; g < 5; g++) {
    int nl0 = w * 20 + g * 4;
    float z1[4] = {0.f, 0.f, 0.f, 0.f}, z2[4] = {0.f, 0.f, 0.f, 0.f};
#pragma unroll 8
    for (int d = 0; d < 64; d++) {
      float m1v = mu_s[l * 65 + d];
      float m2v = mu_s[l2 * 65 + d];
#pragma unroll
      for (int nb = 0; nb < 4; nb++) {
        float dv = d_s[(nl0 + nb) * 68 + d];
        z1[nb] += m1v * dv;
        z2[nb] += m2v * dv;
      }
    }
#pragma unroll
    for (int nb = 0; nb < 4; nb++) {
      float g1 = TEMP * z1[nb];
      float g2 = has2 ? TEMP * z2[nb] : -1e30f;
      float m = wredMax(fmaxf(g1, g2));
      float e1 = expf(g1 - m);
      float e2 = has2 ? expf(g2 - m) : 0.f;
      float inv = 1.0f / wredSum(e1 + e2);
      int nl = nl0 + nb;
      if (MODE == 0) {
        r_s[nl * KC + l] = e1 * inv;
        if (has2) r_s[nl * KC + 64 + l] = e2 * inv;
      } else {
        size_t n = (size_t)blk * CHB + nl;
        rout[n * KC + l] = e1 * inv;
        if (has2) rout[n * KC + 64 + l] = e2 * inv;
        distout[n * KC + l] = z1[nb];
        if (has2) distout[n * KC + 64 + l] = z2[nb];
      }
    }
  }
  if (MODE == 0) {
    __syncthreads();
    int tx = tid & 15, ky = tid >> 4;
    float acc[7][4] = {};
    float accr[7] = {};
    for (int j = 0; j < CHB; j++) {
      float4 dv = *(const float4*)&d_s[j * 68 + (tx << 2)];
#pragma unroll
      for (int jj = 0; jj < 7; jj++) {
        int kk = ky + (jj << 4);
        if (kk < KC) {
          float rv = r_s[j * KC + kk];
          acc[jj][0] += rv * dv.x; acc[jj][1] += rv * dv.y;
          acc[jj][2] += rv * dv.z; acc[jj][3] += rv * dv.w;
          if (tx == 0) accr[jj] += rv;
        }
      }
    }
#pragma unroll
    for (int jj = 0; jj < 7; jj++) {
      int kk = ky + (jj << 4);
      if (kk < KC) {
        float* p = pcm + (size_t)blk * 6400 + kk * 64 + (tx << 2);
        p[0] = acc[jj][0]; p[1] = acc[jj][1]; p[2] = acc[jj][2]; p[3] = acc[jj][3];
        if (tx == 0) pcr[blk * KC + kk] = accr[jj];
      }
    }
  }
}

// mu[k][d] = sum_b pcm[b][k*64+d] / sum_b pcr[b][k]
__global__ __launch_bounds__(256) void muupd_kernel(const float* __restrict__ pcm,
    const float* __restrict__ pcr, float* __restrict__ mu,
    int it, const int* __restrict__ niter) {
  if (it > niter[0]) return;
  __shared__ float part[4][64];
  __shared__ float red[4];
  int k = blockIdx.x, tid = threadIdx.x;
  int d = tid & 63, bg = tid >> 6;
  float s = 0.f;
  for (int b = bg; b < NPART; b += 4)
    s += pcm[(size_t)b * 6400 + k * 64 + d];
  part[bg][d] = s;
  float c = (tid < NPART) ? pcr[tid * KC + k] : 0.f;
  c = wredSum(c);
  if ((tid & 63) == 0) red[tid >> 6] = c;
  __syncthreads();
  if (tid < 64) {
    float cr = red[0] + red[1] + red[2] + red[3];
    mu[k * 64 + tid] = (part[0][tid] + part[1][tid] + part[2][tid] + part[3][tid]) / cr;
  }
}

__global__ void copy_f(const float* __restrict__ a, float* __restrict__ b, int n) {
  int i = blockIdx.x * 256 + threadIdx.x;
  if (i < n) b[i] = a[i];
}

extern "C" void kernel_launch(void* const* d_in, const int* in_sizes, int n_in,
                              void* d_out, int out_size, void* d_ws, size_t ws_size,
                              hipStream_t stream) {
  const float* x    = (const float*)d_in[0];
  const float* W1   = (const float*)d_in[1];
  const float* asr1 = (const float*)d_in[2];
  const float* ads1 = (const float*)d_in[3];
  const float* b1   = (const float*)d_in[4];
  const float* W2   = (const float*)d_in[5];
  const float* asr2 = (const float*)d_in[6];
  const float* ads2 = (const float*)d_in[7];
  const float* b2   = (const float*)d_in[8];
  const float* mu0  = (const float*)d_in[9];
  const int*   ei   = (const int*)d_in[10];
  const int*   nit  = (const int*)d_in[11];

  float* f = (float*)d_ws;
  float* h1   = f;  f += (size_t)Nn * C1;
  float* h1o  = f;  f += (size_t)Nn * C1;
  float* as1  = f;  f += Nn * 2;
  float* ad1  = f;  f += Nn * 2;
  float* h2   = f;  f += (size_t)Nn * C2;
  float* as2  = f;  f += Nn;
  float* ad2  = f;  f += Nn;
  float* dn   = f;  f += (size_t)Nn * C2;
  float* pcm  = f;  f += (size_t)NPART * 6400;
  float* pcr  = f;  f += NPART * KC;
  float* mu   = f;  f += KC * C2;
  int* ip = (int*)f;
  int* deg   = ip;  ip += Nn;
  int* rowp  = ip;  ip += Nn + 1;
  int* curs  = ip;  ip += Nn;
  int* esort = ip;  ip += ETOT;

  float* out_mu = (float*)d_out;
  float* out_r  = out_mu + KC * C2;
  float* out_e  = out_r + (size_t)Nn * KC;
  float* out_d  = out_e + (size_t)Nn * C2;

  hipMemsetAsync(deg, 0, Nn * sizeof(int), stream);
  hist_kernel<<<(ETOT + 255) / 256, 256, 0, stream>>>(ei, deg);
  scan2_kernel<<<1, 1024, 0, stream>>>(deg, rowp, curs);
  scatter_kernel<<<(ETOT + 255) / 256, 256, 0, stream>>>(ei, curs, esort);

  gemm128<<<dim3(157, 2), 256, 0, stream>>>(x, W1, h1, Nn, C1, NF);
  alpha1_kernel<<<5000, 256, 0, stream>>>(h1, asr1, ads1, as1, ad1);
  agg1_kernel<<<Nn, 256, 0, stream>>>(h1, as1, ad1, b1, ei, rowp, esort, h1o);

  gemm_nt<<<dim3(313, 1), 256, 0, stream>>>(h1o, W2, h2, Nn, C2, C1);
  alpha2_kernel<<<5000, 256, 0, stream>>>(h2, asr2, ads2, as2, ad2);
  agg2_kernel<<<Nn, 64, 0, stream>>>(h2, as2, ad2, b2, ei, rowp, esort, out_e, dn);

  for (int it = 0; it < 12; it++) {   // device-guarded: runs niter+1 = 11 updates
    fused_ac<0><<<NPART, 256, 0, stream>>>(dn, mu0, mu, pcm, pcr, nullptr, nullptr, it, nit);
    muupd_kernel<<<KC, 256, 0, stream>>>(pcm, pcr, mu, it, nit);
  }
  fused_ac<1><<<NPART, 256, 0, stream>>>(dn, mu0, mu, nullptr, nullptr, out_r, out_d, 0, nit);
  copy_f<<<25, 256, 0, stream>>>(mu, out_mu, KC * C2);
}

// Round 4
// 1146.138 us; speedup vs baseline: 1.2413x; 1.0238x over previous
//
#include <hip/hip_runtime.h>
#include <math.h>

#define Nn 20000
#define Ee 640000
#define ETOT 660000   // Ee + Nn self loops
#define NF 512
#define C1 256        // HEADS*NHID
#define C2 64         // NOUT
#define KC 100
#define TEMP 5.0f
#define NSLOPE 0.2f
#define NPART 250     // blocks for fused assign+cmean (250*80 = 20000 exactly)
#define CHB 80        // nodes per fused block

__device__ __forceinline__ float wredSum(float v) {
#pragma unroll
  for (int off = 32; off > 0; off >>= 1) v += __shfl_xor(v, off, 64);
  return v;
}
__device__ __forceinline__ float wredMax(float v) {
#pragma unroll
  for (int off = 32; off > 0; off >>= 1) v = fmaxf(v, __shfl_xor(v, off, 64));
  return v;
}

// ---------------- CSR build ----------------
__global__ void hist_kernel(const int* __restrict__ ei, int* __restrict__ deg) {
  int e = blockIdx.x * 256 + threadIdx.x;
  if (e >= ETOT) return;
  int dst = e < Ee ? ei[Ee + e] : e - Ee;
  atomicAdd(&deg[dst], 1);
}

// single block, 1024 threads; thread t owns 20 elements. 2 barriers total.
__global__ __launch_bounds__(1024) void scan2_kernel(const int* __restrict__ deg,
    int* __restrict__ rowp, int* __restrict__ curs) {
  __shared__ int wsum[16];
  __shared__ int wpre[16];
  int t = threadIdx.x;
  int lane = t & 63, w = t >> 6;
  int loc[20];
  int tot = 0;
  int base = t * 20;
  if (t < 1000) {
#pragma unroll
    for (int i = 0; i < 20; i++) { tot += deg[base + i]; loc[i] = tot; }
  }
  int s = tot;
#pragma unroll
  for (int off = 1; off < 64; off <<= 1) {
    int u = __shfl_up(s, off, 64);
    if (lane >= off) s += u;
  }
  if (lane == 63) wsum[w] = s;
  __syncthreads();
  if (t == 0) {
    int c = 0;
#pragma unroll
    for (int i = 0; i < 16; i++) { c += wsum[i]; wpre[i] = c; }
    rowp[0] = 0;
  }
  __syncthreads();
  int p = (w > 0 ? wpre[w - 1] : 0) + s - tot;   // exclusive prefix for this thread
  if (t < 1000) {
    int prev = 0;
#pragma unroll
    for (int i = 0; i < 20; i++) {
      rowp[base + i + 1] = p + loc[i];
      curs[base + i] = p + prev;
      prev = loc[i];
    }
  }
}

__global__ void scatter_kernel(const int* __restrict__ ei, int* __restrict__ curs,
                               int* __restrict__ ssort, int* __restrict__ dsort) {
  int e = blockIdx.x * 256 + threadIdx.x;
  if (e >= ETOT) return;
  int src = e < Ee ? ei[e] : e - Ee;
  int dst = e < Ee ? ei[Ee + e] : e - Ee;
  int pos = atomicAdd(&curs[dst], 1);
  ssort[pos] = src;
  dsort[pos] = dst;
}

// ---------------- per-edge logits (LeakyReLU'd), CSR order ----------------
__global__ __launch_bounds__(256) void edge_e1(const int* __restrict__ ssort,
    const int* __restrict__ dsort, const float* __restrict__ asn,
    const float* __restrict__ adn, float2* __restrict__ eb) {
  int i = blockIdx.x * 256 + threadIdx.x;
  if (i >= ETOT) return;
  int s = ssort[i], d = dsort[i];
  float2 a = ((const float2*)asn)[s];
  float2 b = ((const float2*)adn)[d];
  float e0 = a.x + b.x, e1 = a.y + b.y;
  e0 = e0 > 0.f ? e0 : NSLOPE * e0;
  e1 = e1 > 0.f ? e1 : NSLOPE * e1;
  eb[i] = make_float2(e0, e1);
}

__global__ __launch_bounds__(256) void edge_e2(const int* __restrict__ ssort,
    const int* __restrict__ dsort, const float* __restrict__ asn,
    const float* __restrict__ adn, float* __restrict__ eb) {
  int i = blockIdx.x * 256 + threadIdx.x;
  if (i >= ETOT) return;
  float e = asn[ssort[i]] + adn[dsort[i]];
  eb[i] = e > 0.f ? e : NSLOPE * e;
}

// ---------------- f32 GEMM 128x128: C[M,N] = A[M,K] @ B[N,K]^T ----------------
__global__ __launch_bounds__(256) void gemm128(const float* __restrict__ A,
    const float* __restrict__ B, float* __restrict__ C, int M, int N, int K) {
  __shared__ __align__(16) float As[16][132];
  __shared__ __align__(16) float Bs[16][132];
  int tid = threadIdx.x;
  int bm = blockIdx.x << 7, bn = blockIdx.y << 7;
  int tx = tid & 15, ty = tid >> 4;
  int r0 = tid >> 2;            // 0..63
  int c0 = (tid & 3) << 2;      // 0,4,8,12
  float acc[2][2][4][4] = {};
  for (int k0 = 0; k0 < K; k0 += 16) {
    float4 a0 = make_float4(0.f, 0.f, 0.f, 0.f), a1 = a0;
    int am0 = bm + r0, am1 = bm + 64 + r0;
    if (am0 < M) a0 = *(const float4*)(A + (size_t)am0 * K + k0 + c0);
    if (am1 < M) a1 = *(const float4*)(A + (size_t)am1 * K + k0 + c0);
    float4 b0 = *(const float4*)(B + (size_t)(bn + r0) * K + k0 + c0);
    float4 b1 = *(const float4*)(B + (size_t)(bn + 64 + r0) * K + k0 + c0);
    __syncthreads();
    As[c0 + 0][r0] = a0.x; As[c0 + 1][r0] = a0.y; As[c0 + 2][r0] = a0.z; As[c0 + 3][r0] = a0.w;
    As[c0 + 0][64 + r0] = a1.x; As[c0 + 1][64 + r0] = a1.y; As[c0 + 2][64 + r0] = a1.z; As[c0 + 3][64 + r0] = a1.w;
    Bs[c0 + 0][r0] = b0.x; Bs[c0 + 1][r0] = b0.y; Bs[c0 + 2][r0] = b0.z; Bs[c0 + 3][r0] = b0.w;
    Bs[c0 + 0][64 + r0] = b1.x; Bs[c0 + 1][64 + r0] = b1.y; Bs[c0 + 2][64 + r0] = b1.z; Bs[c0 + 3][64 + r0] = b1.w;
    __syncthreads();
#pragma unroll
    for (int k = 0; k < 16; k++) {
      float4 av0 = *(const float4*)&As[k][ty << 2];
      float4 av1 = *(const float4*)&As[k][64 + (ty << 2)];
      float4 bv0 = *(const float4*)&Bs[k][tx << 2];
      float4 bv1 = *(const float4*)&Bs[k][64 + (tx << 2)];
      float aa[2][4] = {{av0.x, av0.y, av0.z, av0.w}, {av1.x, av1.y, av1.z, av1.w}};
      float bb[2][4] = {{bv0.x, bv0.y, bv0.z, bv0.w}, {bv1.x, bv1.y, bv1.z, bv1.w}};
#pragma unroll
      for (int im = 0; im < 2; im++)
#pragma unroll
        for (int i = 0; i < 4; i++)
#pragma unroll
          for (int jn = 0; jn < 2; jn++)
#pragma unroll
            for (int j = 0; j < 4; j++)
              acc[im][jn][i][j] += aa[im][i] * bb[jn][j];
    }
  }
#pragma unroll
  for (int im = 0; im < 2; im++)
#pragma unroll
    for (int i = 0; i < 4; i++) {
      int row = bm + (im << 6) + (ty << 2) + i;
      if (row < M) {
#pragma unroll
        for (int jn = 0; jn < 2; jn++) {
          float4 v = make_float4(acc[im][jn][i][0], acc[im][jn][i][1],
                                 acc[im][jn][i][2], acc[im][jn][i][3]);
          *(float4*)(C + (size_t)row * N + bn + (jn << 6) + (tx << 2)) = v;
        }
      }
    }
}

// ---------------- f32 GEMM 64x64 (for small N) ----------------
__global__ __launch_bounds__(256) void gemm_nt(const float* __restrict__ A,
    const float* __restrict__ B, float* __restrict__ C, int M, int N, int K) {
  __shared__ __align__(16) float As[16][68];
  __shared__ __align__(16) float Bs[16][68];
  int tid = threadIdx.x;
  int bm = blockIdx.x << 6, bn = blockIdx.y << 6;
  int lr = tid >> 2;
  int lc = (tid & 3) << 2;
  int tx = tid & 15, ty = tid >> 4;
  float acc[4][4] = {};
  for (int k0 = 0; k0 < K; k0 += 16) {
    int am = bm + lr;
    float4 av = make_float4(0.f, 0.f, 0.f, 0.f);
    if (am < M) av = *(const float4*)(A + (size_t)am * K + k0 + lc);
    float4 bv = *(const float4*)(B + (size_t)(bn + lr) * K + k0 + lc);
    __syncthreads();
    As[lc + 0][lr] = av.x; As[lc + 1][lr] = av.y; As[lc + 2][lr] = av.z; As[lc + 3][lr] = av.w;
    Bs[lc + 0][lr] = bv.x; Bs[lc + 1][lr] = bv.y; Bs[lc + 2][lr] = bv.z; Bs[lc + 3][lr] = bv.w;
    __syncthreads();
#pragma unroll
    for (int k = 0; k < 16; k++) {
      float4 a = *(const float4*)&As[k][ty << 2];
      float4 b = *(const float4*)&Bs[k][tx << 2];
      float aa[4] = {a.x, a.y, a.z, a.w};
      float bb[4] = {b.x, b.y, b.z, b.w};
#pragma unroll
      for (int i = 0; i < 4; i++)
#pragma unroll
        for (int j = 0; j < 4; j++) acc[i][j] += aa[i] * bb[j];
    }
  }
#pragma unroll
  for (int i = 0; i < 4; i++) {
    int row = bm + (ty << 2) + i;
    if (row < M) {
#pragma unroll
      for (int j = 0; j < 4; j++)
        C[(size_t)row * N + bn + (tx << 2) + j] = acc[i][j];
    }
  }
}

// ---------------- per-node attention scalars ----------------
__global__ __launch_bounds__(256) void alpha1_kernel(const float* __restrict__ h,
    const float* __restrict__ a_src, const float* __restrict__ a_dst,
    float* __restrict__ asn, float* __restrict__ adn) {
  int l = threadIdx.x & 63;
  int n = (blockIdx.x << 2) + (threadIdx.x >> 6);
  if (n >= Nn) return;
  const float* hr = h + (size_t)n * C1;
  float h0 = hr[l], h1v = hr[64 + l], h2v = hr[128 + l], h3v = hr[192 + l];
  float ps0 = h0 * a_src[l] + h1v * a_src[64 + l];
  float pd0 = h0 * a_dst[l] + h1v * a_dst[64 + l];
  float ps1 = h2v * a_src[128 + l] + h3v * a_src[192 + l];
  float pd1 = h2v * a_dst[128 + l] + h3v * a_dst[192 + l];
  ps0 = wredSum(ps0); pd0 = wredSum(pd0); ps1 = wredSum(ps1); pd1 = wredSum(pd1);
  if (l == 0) {
    asn[2 * n] = ps0; asn[2 * n + 1] = ps1;
    adn[2 * n] = pd0; adn[2 * n + 1] = pd1;
  }
}

__global__ __launch_bounds__(256) void alpha2_kernel(const float* __restrict__ h,
    const float* __restrict__ a_src, const float* __restrict__ a_dst,
    float* __restrict__ asn, float* __restrict__ adn) {
  int l = threadIdx.x & 63;
  int n = (blockIdx.x << 2) + (threadIdx.x >> 6);
  if (n >= Nn) return;
  float v = h[(size_t)n * C2 + l];
  float ps = wredSum(v * a_src[l]);
  float pd = wredSum(v * a_dst[l]);
  if (l == 0) { asn[n] = ps; adn[n] = pd; }
}

// ---------------- layer 1: online segment softmax + float4 gather + ELU ----------------
__global__ __launch_bounds__(256) void agg1_kernel(const float* __restrict__ h,
    const float2* __restrict__ eb, const int* __restrict__ ssort,
    const float* __restrict__ b1, const int* __restrict__ rowp,
    float* __restrict__ ho) {
  __shared__ float redm[8], reds[8];
  __shared__ __align__(16) float slab[4][256];
  int n = blockIdx.x, tid = threadIdx.x;
  int w = tid >> 6, l = tid & 63;
  int lo = rowp[n], hi = rowp[n + 1];
  // phase 1: online softmax (both heads), coalesced edge-buffer read
  float m0 = -1e30f, s0 = 0.f, m1 = -1e30f, s1 = 0.f;
  for (int i = lo + tid; i < hi; i += 256) {
    float2 e = eb[i];
    if (e.x > m0) { s0 = s0 * __expf(m0 - e.x) + 1.f; m0 = e.x; }
    else s0 += __expf(e.x - m0);
    if (e.y > m1) { s1 = s1 * __expf(m1 - e.y) + 1.f; m1 = e.y; }
    else s1 += __expf(e.y - m1);
  }
#pragma unroll
  for (int off = 32; off > 0; off >>= 1) {
    float om = __shfl_xor(m0, off, 64), os = __shfl_xor(s0, off, 64);
    float nm = fmaxf(m0, om);
    s0 = s0 * __expf(m0 - nm) + os * __expf(om - nm); m0 = nm;
    om = __shfl_xor(m1, off, 64); os = __shfl_xor(s1, off, 64);
    nm = fmaxf(m1, om);
    s1 = s1 * __expf(m1 - nm) + os * __expf(om - nm); m1 = nm;
  }
  if (l == 0) { redm[w] = m0; reds[w] = s0; redm[4 + w] = m1; reds[4 + w] = s1; }
  __syncthreads();
  float M0 = fmaxf(fmaxf(redm[0], redm[1]), fmaxf(redm[2], redm[3]));
  float M1 = fmaxf(fmaxf(redm[4], redm[5]), fmaxf(redm[6], redm[7]));
  float S0 = reds[0] * __expf(redm[0] - M0) + reds[1] * __expf(redm[1] - M0)
           + reds[2] * __expf(redm[2] - M0) + reds[3] * __expf(redm[3] - M0);
  float S1 = reds[4] * __expf(redm[4] - M1) + reds[5] * __expf(redm[5] - M1)
           + reds[6] * __expf(redm[6] - M1) + reds[7] * __expf(redm[7] - M1);
  float inv0 = 1.f / (S0 + 1e-16f), inv1 = 1.f / (S1 + 1e-16f);
  // phase 2: each wave covers all 256 channels (float4/lane), strides edges by 4
  const bool lo_head = (l < 32);
  float Msel = lo_head ? M0 : M1;
  float isel = lo_head ? inv0 : inv1;
  int ch = l << 2;
  int deg = hi - lo;
  float4 accA = {0.f, 0.f, 0.f, 0.f}, accB = {0.f, 0.f, 0.f, 0.f};
  int j = w;
  for (; j + 4 < deg; j += 8) {
    int i0 = lo + j, i1 = lo + j + 4;
    float2 eA = eb[i0];
    float2 eB = eb[i1];
    int sA = ssort[i0], sB = ssort[i1];
    float4 ha = *(const float4*)(h + (size_t)sA * C1 + ch);
    float4 hb = *(const float4*)(h + (size_t)sB * C1 + ch);
    float wtA = __expf((lo_head ? eA.x : eA.y) - Msel) * isel;
    float wtB = __expf((lo_head ? eB.x : eB.y) - Msel) * isel;
    accA.x += wtA * ha.x; accA.y += wtA * ha.y; accA.z += wtA * ha.z; accA.w += wtA * ha.w;
    accB.x += wtB * hb.x; accB.y += wtB * hb.y; accB.z += wtB * hb.z; accB.w += wtB * hb.w;
  }
  if (j < deg) {
    int i0 = lo + j;
    float2 eA = eb[i0];
    int sA = ssort[i0];
    float4 ha = *(const float4*)(h + (size_t)sA * C1 + ch);
    float wtA = __expf((lo_head ? eA.x : eA.y) - Msel) * isel;
    accA.x += wtA * ha.x; accA.y += wtA * ha.y; accA.z += wtA * ha.z; accA.w += wtA * ha.w;
  }
  accA.x += accB.x; accA.y += accB.y; accA.z += accB.z; accA.w += accB.w;
  *(float4*)&slab[w][ch] = accA;
  __syncthreads();
  float v = slab[0][tid] + slab[1][tid] + slab[2][tid] + slab[3][tid] + b1[tid];
  ho[(size_t)n * C1 + tid] = v > 0.f ? v : __expf(v) - 1.0f;   // ELU
}

// ---------------- layer 2: wave-per-node, fused softmax+gather+normalize ----------------
__global__ __launch_bounds__(256) void agg2_kernel(const float* __restrict__ h,
    const float* __restrict__ eb, const int* __restrict__ ssort,
    const float* __restrict__ b2, const int* __restrict__ rowp,
    float* __restrict__ emb, float* __restrict__ dnrm) {
  int tid = threadIdx.x;
  int w = tid >> 6, l = tid & 63;
  int n = (blockIdx.x << 2) + w;
  int lo = rowp[n], hi = rowp[n + 1];
  float m = -1e30f, s = 0.f;
  for (int i = lo + l; i < hi; i += 64) {
    float e = eb[i];
    if (e > m) { s = s * __expf(m - e) + 1.f; m = e; }
    else s += __expf(e - m);
  }
#pragma unroll
  for (int off = 32; off > 0; off >>= 1) {
    float om = __shfl_xor(m, off, 64), os = __shfl_xor(s, off, 64);
    float nm = fmaxf(m, om);
    s = s * __expf(m - nm) + os * __expf(om - nm); m = nm;
  }
  float inv = 1.f / (s + 1e-16f);
  int g = l >> 4, lg = l & 15, ch = lg << 2;
  int deg = hi - lo;
  float4 accA = {0.f, 0.f, 0.f, 0.f}, accB = {0.f, 0.f, 0.f, 0.f};
  int j = g;
  for (; j + 4 < deg; j += 8) {
    int i0 = lo + j, i1 = lo + j + 4;
    float eA = eb[i0], eB = eb[i1];
    int sA = ssort[i0], sB = ssort[i1];
    float4 ha = *(const float4*)(h + (size_t)sA * C2 + ch);
    float4 hb = *(const float4*)(h + (size_t)sB * C2 + ch);
    float wtA = __expf(eA - m) * inv;
    float wtB = __expf(eB - m) * inv;
    accA.x += wtA * ha.x; accA.y += wtA * ha.y; accA.z += wtA * ha.z; accA.w += wtA * ha.w;
    accB.x += wtB * hb.x; accB.y += wtB * hb.y; accB.z += wtB * hb.z; accB.w += wtB * hb.w;
  }
  if (j < deg) {
    int i0 = lo + j;
    float eA = eb[i0];
    int sA = ssort[i0];
    float4 ha = *(const float4*)(h + (size_t)sA * C2 + ch);
    float wtA = __expf(eA - m) * inv;
    accA.x += wtA * ha.x; accA.y += wtA * ha.y; accA.z += wtA * ha.z; accA.w += wtA * ha.w;
  }
  accA.x += accB.x; accA.y += accB.y; accA.z += accB.z; accA.w += accB.w;
#pragma unroll
  for (int off = 16; off <= 32; off <<= 1) {
    accA.x += __shfl_xor(accA.x, off, 64);
    accA.y += __shfl_xor(accA.y, off, 64);
    accA.z += __shfl_xor(accA.z, off, 64);
    accA.w += __shfl_xor(accA.w, off, 64);
  }
  float4 bv = *(const float4*)(b2 + ch);
  float e0 = accA.x + bv.x + 1e-6f;
  float e1 = accA.y + bv.y + 1e-6f;
  float e2 = accA.z + bv.z + 1e-6f;
  float e3 = accA.w + bv.w + 1e-6f;
  float dot = e0 * e0 + e1 * e1 + e2 * e2 + e3 * e3;
#pragma unroll
  for (int off = 1; off < 16; off <<= 1) dot += __shfl_xor(dot, off, 64);
  float invn = 1.f / sqrtf(dot);
  if (g == 0) {
    *(float4*)(emb + (size_t)n * C2 + ch) = make_float4(e0, e1, e2, e3);
    *(float4*)(dnrm + (size_t)n * C2 + ch) =
        make_float4(e0 * invn, e1 * invn, e2 * invn, e3 * invn);
  }
}

// ---------------- clustering: fused assign (+partial cluster-mean) ----------------
template <int MODE>
__global__ __launch_bounds__(256) void fused_ac(
    const float* __restrict__ dnp, const float* __restrict__ mu_init,
    const float* __restrict__ mu, float* __restrict__ pcm, float* __restrict__ pcr,
    float* __restrict__ rout, float* __restrict__ distout,
    int it, const int* __restrict__ niter) {
  if (MODE == 0) { if (it > niter[0]) return; }
  __shared__ float mu_s[KC * 65];
  __shared__ __align__(16) float d_s[CHB * 68];
  __shared__ float r_s[CHB * KC];
  int tid = threadIdx.x, blk = blockIdx.x;
  const float* msrc = (MODE == 0 && it == 0) ? mu_init : mu;
  for (int idx = tid; idx < KC * 64; idx += 256)
    mu_s[(idx >> 6) * 65 + (idx & 63)] = msrc[idx];
  for (int idx = tid; idx < CHB * 64; idx += 256) {
    int row = idx >> 6, col = idx & 63;
    d_s[row * 68 + col] = dnp[(size_t)blk * (CHB * 64) + idx];
  }
  __syncthreads();
  int w = tid >> 6, l = tid & 63;
  const bool has2 = l < (KC - 64);
  int l2 = has2 ? 64 + l : l;
  for (int g = 0; g < 5; g++) {
    int nl0 = w * 20 + g * 4;
    float z1[4] = {0.f, 0.f, 0.f, 0.f}, z2[4] = {0.f, 0.f, 0.f, 0.f};
#pragma unroll 8
    for (int d = 0; d < 64; d++) {
      float m1v = mu_s[l * 65 + d];
      float m2v = mu_s[l2 * 65 + d];
#pragma unroll
      for (int nb = 0; nb < 4; nb++) {
        float dv = d_s[(nl0 + nb) * 68 + d];
        z1[nb] += m1v * dv;
        z2[nb] += m2v * dv;
      }
    }
#pragma unroll
    for (int nb = 0; nb < 4; nb++) {
      float g1 = TEMP * z1[nb];
      float g2 = has2 ? TEMP * z2[nb] : -1e30f;
      float m = wredMax(fmaxf(g1, g2));
      float e1 = expf(g1 - m);
      float e2 = has2 ? expf(g2 - m) : 0.f;
      float inv = 1.0f / wredSum(e1 + e2);
      int nl = nl0 + nb;
      if (MODE == 0) {
        r_s[nl * KC + l] = e1 * inv;
        if (has2) r_s[nl * KC + 64 + l] = e2 * inv;
      } else {
        size_t n = (size_t)blk * CHB + nl;
        rout[n * KC + l] = e1 * inv;
        if (has2) rout[n * KC + 64 + l] = e2 * inv;
        distout[n * KC + l] = z1[nb];
        if (has2) distout[n * KC + 64 + l] = z2[nb];
      }
    }
  }
  if (MODE == 0) {
    __syncthreads();
    int tx = tid & 15, ky = tid >> 4;
    float acc[7][4] = {};
    float accr[7] = {};
    for (int j = 0; j < CHB; j++) {
      float4 dv = *(const float4*)&d_s[j * 68 + (tx << 2)];
#pragma unroll
      for (int jj = 0; jj < 7; jj++) {
        int kk = ky + (jj << 4);
        if (kk < KC) {
          float rv = r_s[j * KC + kk];
          acc[jj][0] += rv * dv.x; acc[jj][1] += rv * dv.y;
          acc[jj][2] += rv * dv.z; acc[jj][3] += rv * dv.w;
          if (tx == 0) accr[jj] += rv;
        }
      }
    }
#pragma unroll
    for (int jj = 0; jj < 7; jj++) {
      int kk = ky + (jj << 4);
      if (kk < KC) {
        float* p = pcm + (size_t)blk * 6400 + kk * 64 + (tx << 2);
        p[0] = acc[jj][0]; p[1] = acc[jj][1]; p[2] = acc[jj][2]; p[3] = acc[jj][3];
        if (tx == 0) pcr[blk * KC + kk] = accr[jj];
      }
    }
  }
}

// mu[k][d] = sum_b pcm[b][k*64+d] / sum_b pcr[b][k]
__global__ __launch_bounds__(256) void muupd_kernel(const float* __restrict__ pcm,
    const float* __restrict__ pcr, float* __restrict__ mu,
    int it, const int* __restrict__ niter) {
  if (it > niter[0]) return;
  __shared__ float part[4][64];
  __shared__ float red[4];
  int k = blockIdx.x, tid = threadIdx.x;
  int d = tid & 63, bg = tid >> 6;
  float s = 0.f;
  for (int b = bg; b < NPART; b += 4)
    s += pcm[(size_t)b * 6400 + k * 64 + d];
  part[bg][d] = s;
  float c = (tid < NPART) ? pcr[tid * KC + k] : 0.f;
  c = wredSum(c);
  if ((tid & 63) == 0) red[tid >> 6] = c;
  __syncthreads();
  if (tid < 64) {
    float cr = red[0] + red[1] + red[2] + red[3];
    mu[k * 64 + tid] = (part[0][tid] + part[1][tid] + part[2][tid] + part[3][tid]) / cr;
  }
}

__global__ void copy_f(const float* __restrict__ a, float* __restrict__ b, int n) {
  int i = blockIdx.x * 256 + threadIdx.x;
  if (i < n) b[i] = a[i];
}

extern "C" void kernel_launch(void* const* d_in, const int* in_sizes, int n_in,
                              void* d_out, int out_size, void* d_ws, size_t ws_size,
                              hipStream_t stream) {
  const float* x    = (const float*)d_in[0];
  const float* W1   = (const float*)d_in[1];
  const float* asr1 = (const float*)d_in[2];
  const float* ads1 = (const float*)d_in[3];
  const float* b1   = (const float*)d_in[4];
  const float* W2   = (const float*)d_in[5];
  const float* asr2 = (const float*)d_in[6];
  const float* ads2 = (const float*)d_in[7];
  const float* b2   = (const float*)d_in[8];
  const float* mu0  = (const float*)d_in[9];
  const int*   ei   = (const int*)d_in[10];
  const int*   nit  = (const int*)d_in[11];

  float* f = (float*)d_ws;
  float* h1   = f;  f += (size_t)Nn * C1;
  float* h1o  = f;  f += (size_t)Nn * C1;
  float* as1  = f;  f += Nn * 2;
  float* ad1  = f;  f += Nn * 2;
  float* h2   = f;  f += (size_t)Nn * C2;
  float* as2  = f;  f += Nn;
  float* ad2  = f;  f += Nn;
  float* dn   = f;  f += (size_t)Nn * C2;
  float* pcm  = f;  f += (size_t)NPART * 6400;
  float* pcr  = f;  f += NPART * KC;
  float* mu   = f;  f += KC * C2;
  float2* ebA = (float2*)f; f += (size_t)ETOT * 2;
  float* ebB  = (float*)ebA;            // layer-2 logits reuse layer-1 buffer
  int* ip = (int*)f;
  int* deg   = ip;  ip += Nn;
  int* rowp  = ip;  ip += Nn + 1;
  int* curs  = ip;  ip += Nn;
  int* ssort = ip;  ip += ETOT;
  int* dsort = ip;  ip += ETOT;

  float* out_mu = (float*)d_out;
  float* out_r  = out_mu + KC * C2;
  float* out_e  = out_r + (size_t)Nn * KC;
  float* out_d  = out_e + (size_t)Nn * C2;

  hipMemsetAsync(deg, 0, Nn * sizeof(int), stream);
  hist_kernel<<<(ETOT + 255) / 256, 256, 0, stream>>>(ei, deg);
  scan2_kernel<<<1, 1024, 0, stream>>>(deg, rowp, curs);
  scatter_kernel<<<(ETOT + 255) / 256, 256, 0, stream>>>(ei, curs, ssort, dsort);

  gemm128<<<dim3(157, 2), 256, 0, stream>>>(x, W1, h1, Nn, C1, NF);
  alpha1_kernel<<<5000, 256, 0, stream>>>(h1, asr1, ads1, as1, ad1);
  edge_e1<<<(ETOT + 255) / 256, 256, 0, stream>>>(ssort, dsort, as1, ad1, ebA);
  agg1_kernel<<<Nn, 256, 0, stream>>>(h1, ebA, ssort, b1, rowp, h1o);

  gemm_nt<<<dim3(313, 1), 256, 0, stream>>>(h1o, W2, h2, Nn, C2, C1);
  alpha2_kernel<<<5000, 256, 0, stream>>>(h2, asr2, ads2, as2, ad2);
  edge_e2<<<(ETOT + 255) / 256, 256, 0, stream>>>(ssort, dsort, as2, ad2, ebB);
  agg2_kernel<<<5000, 256, 0, stream>>>(h2, ebB, ssort, b2, rowp, out_e, dn);

  for (int it = 0; it < 12; it++) {   // device-guarded: runs niter+1 = 11 updates
    fused_ac<0><<<NPART, 256, 0, stream>>>(dn, mu0, mu, pcm, pcr, nullptr, nullptr, it, nit);
    muupd_kernel<<<KC, 256, 0, stream>>>(pcm, pcr, mu, it, nit);
  }
  fused_ac<1><<<NPART, 256, 0, stream>>>(dn, mu0, mu, nullptr, nullptr, out_r, out_d, 0, nit);
  copy_f<<<25, 256, 0, stream>>>(mu, out_mu, KC * C2);
}